// Round 3
// baseline (1021.237 us; speedup 1.0000x reference)
//
#include <hip/hip_runtime.h>
#include <math.h>
#include <stdint.h>

// Problem constants (B=8, T=4096, Din=Dout=1024)
#define B_    8
#define T_    4096
#define TP1   4097          // T+1 output rows per batch
#define D_    1024
#define K_    1024
#define M_    32768         // B*T rows

// GEMM tile config
#define BLK_M 128
#define BLK_N 64
#define BK    32

// time-scan chunking: 64 row-chunks of 64 rows (t=1..4096) + row0 entry
#define CH    64
#define NC    65            // carry entries: [row0, chunk0..chunk63]

typedef __attribute__((ext_vector_type(8))) _Float16 f16x8;
typedef __attribute__((ext_vector_type(4))) float    f32x4;

__device__ __forceinline__ float log_g_f(float x) {    // log_g from reference
    return (x >= 0.0f) ? __logf(x + 0.5f) : x - __logf(1.0f + __expf(x));
}

// async 16B/lane global->LDS: lane l writes LDS[ldsbase + l*16] = *(g + lane addr)
__device__ __forceinline__ void g2lds16(const void* g, void* l) {
    __builtin_amdgcn_global_load_lds(
        (const __attribute__((address_space(1))) uint32_t*)g,
        (__attribute__((address_space(3))) uint32_t*)l,
        16, 0, 0);
}

// ---------------------------------------------------------------------------
// K0a: convert X fp32 [M,K] -> f16 fragment-swizzled
//   frag = mtile*32 + kt ; lane l holds (m = mtile*16 + (l&15), k = kt*32 + (l>>4)*8)
// ---------------------------------------------------------------------------
__global__ __launch_bounds__(256) void k_cvt_x(
    const float* __restrict__ X, _Float16* __restrict__ Xs)
{
    int g = blockIdx.x * 256 + threadIdx.x;   // 0 .. M*K/8-1
    int l = g & 63;
    int frag = g >> 6;
    int kt = frag & 31;
    int mt = frag >> 5;
    int m = (mt << 4) + (l & 15);
    int k = (kt << 5) + ((l >> 4) << 3);
    const float4* p = (const float4*)&X[(size_t)m * K_ + k];
    float4 a = p[0], b = p[1];
    f16x8 h;
    h[0]=(_Float16)a.x; h[1]=(_Float16)a.y; h[2]=(_Float16)a.z; h[3]=(_Float16)a.w;
    h[4]=(_Float16)b.x; h[5]=(_Float16)b.y; h[6]=(_Float16)b.z; h[7]=(_Float16)b.w;
    *(f16x8*)&Xs[(size_t)g * 8] = h;
}

// K0b: convert Wi|Wf|Wh fp32 [1024,1024] each -> f16 swizzled, concatenated
__global__ __launch_bounds__(256) void k_cvt_w(
    const float* __restrict__ Wi, const float* __restrict__ Wf,
    const float* __restrict__ Wh, _Float16* __restrict__ Ws)
{
    int g = blockIdx.x * 256 + threadIdx.x;   // 0 .. 3*1024*1024/8-1
    int mat = g >> 17;                        // 131072 lanes-of-8 per matrix
    int r = g & 131071;
    const float* W = (mat == 0) ? Wi : (mat == 1) ? Wf : Wh;
    int l = r & 63;
    int frag = r >> 6;
    int kt = frag & 31;
    int nt = frag >> 5;
    int n = (nt << 4) + (l & 15);
    int k = (kt << 5) + ((l >> 4) << 3);
    const float4* p = (const float4*)&W[(size_t)n * K_ + k];
    float4 a = p[0], b = p[1];
    f16x8 h;
    h[0]=(_Float16)a.x; h[1]=(_Float16)a.y; h[2]=(_Float16)a.z; h[3]=(_Float16)a.w;
    h[4]=(_Float16)b.x; h[5]=(_Float16)b.y; h[6]=(_Float16)b.z; h[7]=(_Float16)b.w;
    *(f16x8*)&Ws[(size_t)g * 8] = h;
}

// ---------------------------------------------------------------------------
// K1: fused triple GEMM (f16 MFMA, global_load_lds staging) + gate math.
//   4-deep LDS pipeline (80 KiB = exactly 2 blocks/CU), counted vmcnt(10)
//   (never 0 in main loop), raw s_barrier, setprio around MFMA cluster.
//   Block order: XCD chunk -> 8m x 8n super-tiles so the ~64 concurrent
//   blocks per XCD have A(2MB)+B(3MB) working set fitting the 4MB L2.
// ---------------------------------------------------------------------------
__device__ __forceinline__ void stage_tile(
    const _Float16* Ag, const _Float16* Bg, int kt,
    _Float16* lAbuf, _Float16* lBbuf, int fa0, int fb0)
{
    g2lds16(Ag + (size_t)(fa0 * 32 + kt) * 512,       lAbuf + fa0 * 512);
    g2lds16(Ag + (size_t)((fa0 + 1) * 32 + kt) * 512, lAbuf + (fa0 + 1) * 512);
#pragma unroll
    for (int j = 0; j < 3; ++j) {
        int fb  = fb0 + j;
        int mat = fb >> 2, nf = fb & 3;
        g2lds16(Bg + ((size_t)mat * 2048 + (size_t)nf * 32 + kt) * 512,
                lBbuf + fb * 512);
    }
}

__device__ __forceinline__ void compute_tile(
    const _Float16* lAbuf, const _Float16* lBbuf,
    int wm, int wnf, int lane, f32x4 acc[3][4][2])
{
    f16x8 af[4];
#pragma unroll
    for (int mt = 0; mt < 4; ++mt)
        af[mt] = *(const f16x8*)&lAbuf[((wm >> 4) + mt) * 512 + lane * 8];
    __builtin_amdgcn_s_setprio(1);
#pragma unroll
    for (int a = 0; a < 3; ++a) {
#pragma unroll
        for (int nt = 0; nt < 2; ++nt) {
            f16x8 bfr = *(const f16x8*)&lBbuf[(a * 4 + wnf + nt) * 512 + lane * 8];
#pragma unroll
            for (int mt = 0; mt < 4; ++mt)
                acc[a][mt][nt] = __builtin_amdgcn_mfma_f32_16x16x32_f16(
                    af[mt], bfr, acc[a][mt][nt], 0, 0, 0);
        }
    }
    __builtin_amdgcn_s_setprio(0);
}

// wait for all but the newest N VMEM ops, then block barrier
#define WAITBAR(N) do {                                         \
    asm volatile("s_waitcnt vmcnt(" #N ")" ::: "memory");       \
    __builtin_amdgcn_s_barrier();                               \
} while (0)

__global__ __launch_bounds__(256) void k_gemm(
    const _Float16* __restrict__ Xs, const _Float16* __restrict__ Ws,
    const float* __restrict__ bi, const float* __restrict__ bfv,
    const float* __restrict__ bh,
    float* __restrict__ ws_a, float* __restrict__ out)
{
    __shared__ __align__(16) _Float16 lA[4][8 * 512];    // 4 x  8 KiB
    __shared__ __align__(16) _Float16 lB[4][12 * 512];   // 4 x 12 KiB

    const int tid  = threadIdx.x;
    const int lane = tid & 63;
    const int w    = tid >> 6;

    // block-order swizzle: XCD x gets 512 consecutive logical tiles, ordered
    // as 8 groups of (8m x 8n) super-tiles; gn fastest so consecutive groups
    // reuse the A panel.
    const int bid = blockIdx.y * (int)gridDim.x + blockIdx.x;  // 0..4095
    const int x   = bid & 7;           // XCD
    const int j   = bid >> 3;          // 0..511 position within XCD chunk
    const int jj  = j & 63;            // position within 64-block super-tile
    const int g   = j >> 6;            // super-tile index 0..7
    const int gn  = g & 1;             // n half (0..1)
    const int gm  = g >> 1;            // m quarter (0..3)
    const int tile_n = gn * 8 + (jj & 7);             // 0..15
    const int tile_m = x * 32 + gm * 8 + (jj >> 3);   // 0..255
    const int n0  = tile_n * BLK_N;
    const int m0  = tile_m * BLK_M;

    const int wm   = (w >> 1) * 64;        // wave row offset
    const int wnf  = (w & 1) * 2;          // wave n-frag offset (0 or 2)
    const int l16  = lane & 15;
    const int q    = lane >> 4;

    // staging assignment (wave-uniform): wave w stages A frags {2w,2w+1},
    // B frags {3w..3w+2} of 12 (fb -> mat=fb>>2, nf=fb&3). 5 loads/wave/tile.
    const int fa0 = w * 2;
    const int fb0 = w * 3;

    const _Float16* Ag = Xs + ((size_t)(m0 >> 4) * 32) * 512 + (size_t)lane * 8;
    const _Float16* Bg = Ws + (size_t)(n0 >> 4) * 32 * 512 + (size_t)lane * 8;

    f32x4 acc[3][4][2];
#pragma unroll
    for (int a = 0; a < 3; ++a)
#pragma unroll
        for (int mt = 0; mt < 4; ++mt)
#pragma unroll
            for (int nt = 0; nt < 2; ++nt) acc[a][mt][nt] = (f32x4)(0.0f);

    // ---- prologue: stage kt=0,1,2 into buffers 0,1,2 ----
    stage_tile(Ag, Bg, 0, lA[0], lB[0], fa0, fb0);
    stage_tile(Ag, Bg, 1, lA[1], lB[1], fa0, fb0);
    stage_tile(Ag, Bg, 2, lA[2], lB[2], fa0, fb0);
    WAITBAR(10);   // kt0's 5 loads landed; kt1/kt2's 10 remain in flight

    // ---- main loop: 7 iters x 4 K-steps = kt 0..27, staging kt 3..30 ----
    // invariant at top of sub-step kt: buf[kt&3] ready; kt+1,kt+2 in flight
    for (int it = 0; it < 7; ++it) {
        const int kt = it * 4;
        stage_tile(Ag, Bg, kt + 3, lA[3], lB[3], fa0, fb0);
        compute_tile(lA[0], lB[0], wm, wnf, lane, acc);       // kt
        WAITBAR(10);  // kt+1 landed; kt+2, kt+3 in flight

        stage_tile(Ag, Bg, kt + 4, lA[0], lB[0], fa0, fb0);
        compute_tile(lA[1], lB[1], wm, wnf, lane, acc);       // kt+1
        WAITBAR(10);

        stage_tile(Ag, Bg, kt + 5, lA[1], lB[1], fa0, fb0);
        compute_tile(lA[2], lB[2], wm, wnf, lane, acc);       // kt+2
        WAITBAR(10);

        stage_tile(Ag, Bg, kt + 6, lA[2], lB[2], fa0, fb0);
        compute_tile(lA[3], lB[3], wm, wnf, lane, acc);       // kt+3
        WAITBAR(10);
    }
    // tail: kt=28..31. outstanding here: 29(5), 30(5).
    stage_tile(Ag, Bg, 31, lA[3], lB[3], fa0, fb0);           // +5 -> 15
    compute_tile(lA[0], lB[0], wm, wnf, lane, acc);           // kt = 28
    WAITBAR(10);  // 29 landed
    compute_tile(lA[1], lB[1], wm, wnf, lane, acc);           // kt = 29
    WAITBAR(5);   // 30 landed
    compute_tile(lA[2], lB[2], wm, wnf, lane, acc);           // kt = 30
    WAITBAR(0);   // 31 landed
    compute_tile(lA[3], lB[3], wm, wnf, lane, acc);           // kt = 31

    // epilogue: gate math. With P = 1+e^{-z}:
    //   log_f = log(Pi) - log(Pi+Pf);  log_i = log(Pf) - log(Pi+Pf)
    // (algebraically identical to -softplus(diff) form, fewer trans ops)
#pragma unroll
    for (int mt = 0; mt < 4; ++mt) {
#pragma unroll
        for (int nt = 0; nt < 2; ++nt) {
            int n = n0 + (wnf + nt) * 16 + l16;
            float biv = bi[n], bfvv = bfv[n], bhv = bh[n];
#pragma unroll
            for (int r = 0; r < 4; ++r) {
                int m = m0 + wm + mt * 16 + q * 4 + r;   // C/D: row=(lane>>4)*4+r, col=lane&15
                float zi = acc[0][mt][nt][r] + biv;
                float zf = acc[1][mt][nt][r] + bfvv;
                float zh = acc[2][mt][nt][r] + bhv;
                float ei = __expf(-zi), ef = __expf(-zf);
                float Pi = 1.0f + ei,  Pf = 1.0f + ef;
                float lS = __logf(Pi + Pf);
                float lf = __logf(Pi) - lS;              // log_f
                float li = __logf(Pf) - lS;              // log_i
                float lg = (zh >= 0.0f) ? __logf(zh + 0.5f)
                                        : zh - __logf(1.0f + __expf(zh));
                float lv = li + lg;
                ws_a[(size_t)m * D_ + n] = lf;
                int b = m >> 12;                          // m / T_
                out[(size_t)(m + b + 1) * D_ + n] = lv;
            }
        }
    }
}

// ---------------------------------------------------------------------------
// K2: fused per-row cumsum (over d) + per-chunk column logsumexp stats.
//   Block = (chunk c of 64 rows, batch b). Wave w handles rows [16w,16w+16):
//   row cumsum via shfl scan -> a* (ws_a), u = lv - a* (out), online (m,s)
//   per lane-owned d. Then 4-wave LDS tree combine -> ctm/cts entry 1+c.
// ---------------------------------------------------------------------------
__global__ __launch_bounds__(256) void k_cumchunk(
    float* __restrict__ ws_a, float* __restrict__ out,
    float* __restrict__ ctm, float* __restrict__ cts)
{
    const int c    = blockIdx.x;       // 0..63
    const int b    = blockIdx.y;
    const int tid  = threadIdx.x;
    const int lane = tid & 63;
    const int w    = tid >> 6;

    __shared__ float smm[4][1024];
    __shared__ float sss[4][1024];

    float cm[16], cs[16];
#pragma unroll
    for (int j = 0; j < 16; ++j) { cm[j] = -__builtin_inff(); cs[j] = 0.0f; }

    const int r0 = c * CH + w * 16;    // row offset within batch (bt index)
    for (int i = 0; i < 16; ++i) {
        const int r = r0 + i;
        float* pa = ws_a + ((size_t)b * T_ + r) * D_;
        float* pu = out + ((size_t)b * TP1 + r + 1) * D_;

        float vals[16];
#pragma unroll
        for (int j = 0; j < 4; ++j) {
            float4 v = *(const float4*)&pa[lane * 16 + j * 4];
            vals[j*4+0]=v.x; vals[j*4+1]=v.y; vals[j*4+2]=v.z; vals[j*4+3]=v.w;
        }
        float s = 0.0f;
#pragma unroll
        for (int j = 0; j < 16; ++j) s += vals[j];
        float inc = s;
#pragma unroll
        for (int off = 1; off < 64; off <<= 1) {
            float nv = __shfl_up(inc, off);
            if (lane >= off) inc += nv;
        }
        float run = inc - s;                       // exclusive prefix of lane sums
#pragma unroll
        for (int j = 0; j < 16; ++j) { run += vals[j]; vals[j] = run; }  // a*

#pragma unroll
        for (int j = 0; j < 4; ++j) {
            float4 lv4 = *(const float4*)&pu[lane * 16 + j * 4];
            float4 a4; a4.x = vals[j*4]; a4.y = vals[j*4+1];
                       a4.z = vals[j*4+2]; a4.w = vals[j*4+3];
            float4 u4; u4.x = lv4.x - a4.x; u4.y = lv4.y - a4.y;
                       u4.z = lv4.z - a4.z; u4.w = lv4.w - a4.w;
            *(float4*)&pa[lane * 16 + j * 4] = a4;
            *(float4*)&pu[lane * 16 + j * 4] = u4;
            float uu[4] = {u4.x, u4.y, u4.z, u4.w};
#pragma unroll
            for (int e = 0; e < 4; ++e) {
                int jj = j * 4 + e;
                float mn = fmaxf(cm[jj], uu[e]);
                cs[jj] = cs[jj] * __expf(cm[jj] - mn) + __expf(uu[e] - mn);
                cm[jj] = mn;
            }
        }
    }

#pragma unroll
    for (int j = 0; j < 16; ++j) {
        smm[w][lane * 16 + j] = cm[j];
        sss[w][lane * 16 + j] = cs[j];
    }
    __syncthreads();

    {   // each thread combines 4 d-columns across the 4 waves
        int d0 = tid * 4;
        size_t ci = ((size_t)b * NC + 1 + c) * D_ + d0;
#pragma unroll
        for (int e = 0; e < 4; ++e) {
            int d = d0 + e;
            float M = smm[0][d], S = sss[0][d];
#pragma unroll
            for (int ww = 1; ww < 4; ++ww) {
                float m2 = smm[ww][d], s2 = sss[ww][d];
                float Mn = fmaxf(M, m2);
                S = S * __expf(M - Mn) + s2 * __expf(m2 - Mn);
                M = Mn;
            }
            ctm[ci + e] = M;
            cts[ci + e] = S;
        }
    }
}

// K2b: out row 0 per batch: u[b,0,d] = log_g(h0); also carry entry 0 stats
__global__ void k_h0(const float* __restrict__ h0, float* __restrict__ out,
                     float* __restrict__ ctm, float* __restrict__ cts)
{
    int i = blockIdx.x * 256 + threadIdx.x;    // 0..8191
    int b = i >> 10, d = i & 1023;
    float u0 = log_g_f(h0[i]);
    out[(size_t)b * TP1 * D_ + d] = u0;
    ctm[(size_t)b * NC * D_ + d] = u0;         // chunk entry 0 = row 0 alone
    cts[(size_t)b * NC * D_ + d] = 1.0f;
}

// K4: exclusive chunk-carry logcumsumexp across NC entries (8192 indep threads)
__global__ __launch_bounds__(256) void k_carry(
    const float* __restrict__ ctm, const float* __restrict__ cts,
    float* __restrict__ carry)
{
    int i = blockIdx.x * 256 + threadIdx.x;    // 0..8191
    int b = i >> 10, d = i & 1023;
    float m = -__builtin_inff(), s = 0.0f;
    for (int c = 0; c < NC; ++c) {
        size_t ci = ((size_t)b * NC + c) * D_ + d;
        carry[ci] = (s == 0.0f) ? -__builtin_inff() : (m + __logf(s));
        float m2 = ctm[ci], s2 = cts[ci];
        float M = fmaxf(m, m2);
        s = s * __expf(m - M) + s2 * __expf(m2 - M);
        m = M;
    }
}

// ---------------------------------------------------------------------------
// K5: finalize: rescan chunk with carry-in, out = exp(a* + m) * s — float4
//   carry entry 0 covers row 0 only; entry c>=1 covers rows [1+64(c-1), 64c].
// ---------------------------------------------------------------------------
__global__ __launch_bounds__(256) void k_final(
    const float* __restrict__ ws_a, const float* __restrict__ carry,
    float* __restrict__ out)
{
    int c = blockIdx.x, b = blockIdx.y;        // c in 0..NC-1
    int d = threadIdx.x * 4;
    int t0 = (c == 0) ? 0 : ((c - 1) * CH + 1);
    int t1 = (c == 0) ? 1 : (c * CH + 1);
    float4 v = *(const float4*)&carry[((size_t)b * NC + c) * D_ + d];
    float4 m, s;
    m.x = v.x; s.x = (v.x == -__builtin_inff()) ? 0.f : 1.f;
    m.y = v.y; s.y = (v.y == -__builtin_inff()) ? 0.f : 1.f;
    m.z = v.z; s.z = (v.z == -__builtin_inff()) ? 0.f : 1.f;
    m.w = v.w; s.w = (v.w == -__builtin_inff()) ? 0.f : 1.f;
    for (int t = t0; t < t1; ++t) {
        size_t oi = ((size_t)b * TP1 + t) * D_ + d;
        float4 u = *(const float4*)&out[oi];
        float4 mn;
        mn.x = fmaxf(m.x, u.x); mn.y = fmaxf(m.y, u.y);
        mn.z = fmaxf(m.z, u.z); mn.w = fmaxf(m.w, u.w);
        s.x = s.x * __expf(m.x - mn.x) + __expf(u.x - mn.x);
        s.y = s.y * __expf(m.y - mn.y) + __expf(u.y - mn.y);
        s.z = s.z * __expf(m.z - mn.z) + __expf(u.z - mn.z);
        s.w = s.w * __expf(m.w - mn.w) + __expf(u.w - mn.w);
        m = mn;
        float4 a = make_float4(0.f, 0.f, 0.f, 0.f);
        if (t != 0) a = *(const float4*)&ws_a[((size_t)b * T_ + (t - 1)) * D_ + d];
        float4 o;
        o.x = __expf(a.x + mn.x) * s.x;
        o.y = __expf(a.y + mn.y) * s.y;
        o.z = __expf(a.z + mn.z) * s.z;
        o.w = __expf(a.w + mn.w) * s.w;
        *(float4*)&out[oi] = o;
    }
}

// ---------------------------------------------------------------------------
extern "C" void kernel_launch(void* const* d_in, const int* in_sizes, int n_in,
                              void* d_out, int out_size, void* d_ws, size_t ws_size,
                              hipStream_t stream)
{
    const float* X   = (const float*)d_in[0];
    const float* h0  = (const float*)d_in[1];
    const float* Wi  = (const float*)d_in[2];
    const float* bi  = (const float*)d_in[3];
    const float* Wf  = (const float*)d_in[4];
    const float* bfv = (const float*)d_in[5];
    const float* Wh  = (const float*)d_in[6];
    const float* bh  = (const float*)d_in[7];
    float* out  = (float*)d_out;

    // ws layout:
    //   [0, 128M)        ws_a  (log_f -> a*)            fp32 M*D
    //   [128M, 192M)     Xs    f16 swizzled X           (dead after k_gemm)
    //   [192M, 198M)     Wsv   f16 swizzled Wi|Wf|Wh
    //   ctm/cts/carry overlay the Xs region after k_gemm (~6.4 MB)
    char* wsb = (char*)d_ws;
    float*    ws_a = (float*)wsb;
    _Float16* Xs   = (_Float16*)(wsb + (size_t)M_ * D_ * 4);
    _Float16* Wsv  = (_Float16*)(wsb + (size_t)M_ * D_ * 4 + (size_t)M_ * K_ * 2);
    float* ctm   = (float*)(wsb + (size_t)M_ * D_ * 4);
    float* cts   = ctm + B_ * NC * D_;
    float* carry = cts + B_ * NC * D_;

    k_cvt_x<<<M_ * K_ / 8 / 256, 256, 0, stream>>>(X, Xs);
    k_cvt_w<<<3 * D_ * K_ / 8 / 256, 256, 0, stream>>>(Wi, Wf, Wh, Wsv);

    dim3 g1(D_ / BLK_N, M_ / BLK_M);          // 16 x 256
    k_gemm<<<g1, 256, 0, stream>>>(Xs, Wsv, bi, bfv, bh, ws_a, out);
    k_h0<<<32, 256, 0, stream>>>(h0, out, ctm, cts);
    k_cumchunk<<<dim3(T_ / CH, B_), 256, 0, stream>>>(ws_a, out, ctm, cts);
    k_carry<<<32, 256, 0, stream>>>(ctm, cts, carry);
    k_final<<<dim3(NC, B_), 256, 0, stream>>>(ws_a, carry, out);
}

// Round 4
// 763.823 us; speedup vs baseline: 1.3370x; 1.3370x over previous
//
#include <hip/hip_runtime.h>
#include <math.h>
#include <stdint.h>

// Problem constants (B=8, T=4096, Din=Dout=1024)
#define B_    8
#define T_    4096
#define TP1   4097          // T+1 output rows per batch
#define D_    1024
#define K_    1024
#define M_    32768         // B*T rows

// GEMM tile config
#define BLK_M 128
#define BLK_N 64
#define BK    32

// time-scan chunking: 64 chunks of 64 rows (t=1..4096); row 0 handled in carry
#define CH    64
#define NCH   64

typedef __attribute__((ext_vector_type(8))) _Float16 f16x8;
typedef __attribute__((ext_vector_type(4))) float    f32x4;

__device__ __forceinline__ float log_g_f(float x) {    // log_g from reference
    return (x >= 0.0f) ? __logf(x + 0.5f) : x - __logf(1.0f + __expf(x));
}

// online logsumexp update
__device__ __forceinline__ void lse_upd(float& m, float& s, float u) {
    float mn = fmaxf(m, u);
    s = s * __expf(m - mn) + __expf(u - mn);
    m = mn;
}

// async 16B/lane global->LDS: lane l writes LDS[ldsbase + l*16] = *(g + lane addr)
__device__ __forceinline__ void g2lds16(const void* g, void* l) {
    __builtin_amdgcn_global_load_lds(
        (const __attribute__((address_space(1))) uint32_t*)g,
        (__attribute__((address_space(3))) uint32_t*)l,
        16, 0, 0);
}

// ---------------------------------------------------------------------------
// K0: combined converts.
//   blocks [0,1536):     Wi|Wf|Wh fp32 -> f16 swizzled (concatenated)
//   blocks [1536,17920): X fp32 [M,K] -> f16 fragment-swizzled
//   frag = mtile*32 + kt ; lane l holds (m = mtile*16 + (l&15), k = kt*32 + (l>>4)*8)
// ---------------------------------------------------------------------------
__global__ __launch_bounds__(256) void k_cvt(
    const float* __restrict__ X, const float* __restrict__ Wi,
    const float* __restrict__ Wf, const float* __restrict__ Wh,
    _Float16* __restrict__ Xs, _Float16* __restrict__ Ws)
{
    int bid = blockIdx.x;
    if (bid < 1536) {
        int g = bid * 256 + threadIdx.x;      // 0 .. 3*1024*1024/8-1
        int mat = g >> 17;                    // 131072 lanes-of-8 per matrix
        int r = g & 131071;
        const float* W = (mat == 0) ? Wi : (mat == 1) ? Wf : Wh;
        int l = r & 63;
        int frag = r >> 6;
        int kt = frag & 31;
        int nt = frag >> 5;
        int n = (nt << 4) + (l & 15);
        int k = (kt << 5) + ((l >> 4) << 3);
        const float4* p = (const float4*)&W[(size_t)n * K_ + k];
        float4 a = p[0], b = p[1];
        f16x8 h;
        h[0]=(_Float16)a.x; h[1]=(_Float16)a.y; h[2]=(_Float16)a.z; h[3]=(_Float16)a.w;
        h[4]=(_Float16)b.x; h[5]=(_Float16)b.y; h[6]=(_Float16)b.z; h[7]=(_Float16)b.w;
        *(f16x8*)&Ws[(size_t)g * 8] = h;
    } else {
        int g = (bid - 1536) * 256 + threadIdx.x;   // 0 .. M*K/8-1
        int l = g & 63;
        int frag = g >> 6;
        int kt = frag & 31;
        int mt = frag >> 5;
        int m = (mt << 4) + (l & 15);
        int k = (kt << 5) + ((l >> 4) << 3);
        const float4* p = (const float4*)&X[(size_t)m * K_ + k];
        float4 a = p[0], b = p[1];
        f16x8 h;
        h[0]=(_Float16)a.x; h[1]=(_Float16)a.y; h[2]=(_Float16)a.z; h[3]=(_Float16)a.w;
        h[4]=(_Float16)b.x; h[5]=(_Float16)b.y; h[6]=(_Float16)b.z; h[7]=(_Float16)b.w;
        *(f16x8*)&Xs[(size_t)g * 8] = h;
    }
}

// ---------------------------------------------------------------------------
// K1: fused triple GEMM (f16 MFMA, global_load_lds staging) + gate math.
//   3-deep LDS pipeline (60 KiB, 2 blocks/CU), counted vmcnt(5) (never 0 in
//   main loop), raw s_barrier, setprio around MFMA cluster, XCD swizzle.
//   (R2-proven schedule; R3's 4-deep/80KiB dropped to 1 block/CU — reverted.)
// ---------------------------------------------------------------------------
__device__ __forceinline__ void stage_tile(
    const _Float16* Ag, const _Float16* Bg, int kt,
    _Float16* lAbuf, _Float16* lBbuf, int fa0, int fb0)
{
    g2lds16(Ag + (size_t)(fa0 * 32 + kt) * 512,       lAbuf + fa0 * 512);
    g2lds16(Ag + (size_t)((fa0 + 1) * 32 + kt) * 512, lAbuf + (fa0 + 1) * 512);
#pragma unroll
    for (int j = 0; j < 3; ++j) {
        int fb  = fb0 + j;
        int mat = fb >> 2, nf = fb & 3;
        g2lds16(Bg + ((size_t)mat * 2048 + (size_t)nf * 32 + kt) * 512,
                lBbuf + fb * 512);
    }
}

__device__ __forceinline__ void compute_tile(
    const _Float16* lAbuf, const _Float16* lBbuf,
    int wm, int wnf, int lane, f32x4 acc[3][4][2])
{
    f16x8 af[4];
#pragma unroll
    for (int mt = 0; mt < 4; ++mt)
        af[mt] = *(const f16x8*)&lAbuf[((wm >> 4) + mt) * 512 + lane * 8];
    __builtin_amdgcn_s_setprio(1);
#pragma unroll
    for (int a = 0; a < 3; ++a) {
#pragma unroll
        for (int nt = 0; nt < 2; ++nt) {
            f16x8 bfr = *(const f16x8*)&lBbuf[(a * 4 + wnf + nt) * 512 + lane * 8];
#pragma unroll
            for (int mt = 0; mt < 4; ++mt)
                acc[a][mt][nt] = __builtin_amdgcn_mfma_f32_16x16x32_f16(
                    af[mt], bfr, acc[a][mt][nt], 0, 0, 0);
        }
    }
    __builtin_amdgcn_s_setprio(0);
}

// wait for all but the newest N VMEM ops, then block barrier
#define WAITBAR(N) do {                                         \
    asm volatile("s_waitcnt vmcnt(" #N ")" ::: "memory");       \
    __builtin_amdgcn_s_barrier();                               \
} while (0)

__global__ __launch_bounds__(256) void k_gemm(
    const _Float16* __restrict__ Xs, const _Float16* __restrict__ Ws,
    const float* __restrict__ bi, const float* __restrict__ bfv,
    const float* __restrict__ bh,
    float* __restrict__ ws_a, float* __restrict__ out)
{
    __shared__ __align__(16) _Float16 lA[3][8 * 512];    // 3 x  8 KiB
    __shared__ __align__(16) _Float16 lB[3][12 * 512];   // 3 x 12 KiB

    const int tid  = threadIdx.x;
    const int lane = tid & 63;
    const int w    = tid >> 6;

    // XCD-aware bijective swizzle (nwg=4096 % 8 == 0): the 16 n-blocks sharing
    // one A-tile land on the same XCD's L2.
    const int bid = blockIdx.y * (int)gridDim.x + blockIdx.x;
    const int cpx = ((int)gridDim.x * (int)gridDim.y) >> 3;   // 512
    const int swz = (bid & 7) * cpx + (bid >> 3);
    const int n0  = (swz & 15) * BLK_N;
    const int m0  = (swz >> 4) * BLK_M;

    const int wm   = (w >> 1) * 64;        // wave row offset
    const int wnf  = (w & 1) * 2;          // wave n-frag offset (0 or 2)
    const int l16  = lane & 15;
    const int q    = lane >> 4;

    // staging assignment (wave-uniform): wave w stages A frags {2w,2w+1},
    // B frags {3w..3w+2} of 12 (fb -> mat=fb>>2, nf=fb&3). 5 loads/wave/tile.
    const int fa0 = w * 2;
    const int fb0 = w * 3;

    const _Float16* Ag = Xs + ((size_t)(m0 >> 4) * 32) * 512 + (size_t)lane * 8;
    const _Float16* Bg = Ws + (size_t)(n0 >> 4) * 32 * 512 + (size_t)lane * 8;

    f32x4 acc[3][4][2];
#pragma unroll
    for (int a = 0; a < 3; ++a)
#pragma unroll
        for (int mt = 0; mt < 4; ++mt)
#pragma unroll
            for (int nt = 0; nt < 2; ++nt) acc[a][mt][nt] = (f32x4)(0.0f);

    // ---- prologue: stage kt=0 (buf0), kt=1 (buf1) ----
    stage_tile(Ag, Bg, 0, lA[0], lB[0], fa0, fb0);
    stage_tile(Ag, Bg, 1, lA[1], lB[1], fa0, fb0);
    WAITBAR(5);   // kt0's 5 loads landed; kt1's 5 may remain in flight

    // ---- main loop: kt = 0..29, unrolled x3 for static buffer indices ----
    // invariant at top of sub-step kt: buf[kt%3] ready; kt+1's loads in flight
    for (int it = 0; it < 10; ++it) {
        const int kt = it * 3;

        stage_tile(Ag, Bg, kt + 2, lA[2], lB[2], fa0, fb0);   // (kt+2)%3 == 2
        compute_tile(lA[0], lB[0], wm, wnf, lane, acc);       // kt
        WAITBAR(5);   // kt+1's landed; kt+2's (5 newest) stay in flight

        stage_tile(Ag, Bg, kt + 3, lA[0], lB[0], fa0, fb0);
        compute_tile(lA[1], lB[1], wm, wnf, lane, acc);       // kt+1
        WAITBAR(5);

        stage_tile(Ag, Bg, kt + 4, lA[1], lB[1], fa0, fb0);
        compute_tile(lA[2], lB[2], wm, wnf, lane, acc);       // kt+2
        WAITBAR(5);
    }
    // tail: kt=30 (buf0) already resident; kt=31 (buf1) needs full drain
    compute_tile(lA[0], lB[0], wm, wnf, lane, acc);           // kt = 30
    WAITBAR(0);
    compute_tile(lA[1], lB[1], wm, wnf, lane, acc);           // kt = 31

    // epilogue: gate math. With P = 1+e^{-z}:
    //   log_f = log(Pi) - log(Pi+Pf);  log_i = log(Pf) - log(Pi+Pf)
    // (algebraically identical to -softplus(diff) form, fewer trans ops)
#pragma unroll
    for (int mt = 0; mt < 4; ++mt) {
#pragma unroll
        for (int nt = 0; nt < 2; ++nt) {
            int n = n0 + (wnf + nt) * 16 + l16;
            float biv = bi[n], bfvv = bfv[n], bhv = bh[n];
#pragma unroll
            for (int r = 0; r < 4; ++r) {
                int m = m0 + wm + mt * 16 + q * 4 + r;   // C/D: row=(lane>>4)*4+r, col=lane&15
                float zi = acc[0][mt][nt][r] + biv;
                float zf = acc[1][mt][nt][r] + bfvv;
                float zh = acc[2][mt][nt][r] + bhv;
                float ei = __expf(-zi), ef = __expf(-zf);
                float Pi = 1.0f + ei,  Pf = 1.0f + ef;
                float lS = __logf(Pi + Pf);
                float lf = __logf(Pi) - lS;              // log_f
                float li = __logf(Pf) - lS;              // log_i
                float lg = (zh >= 0.0f) ? __logf(zh + 0.5f)
                                        : zh - __logf(1.0f + __expf(zh));
                float lv = li + lg;
                ws_a[(size_t)m * D_ + n] = lf;
                int b = m >> 12;                          // m / T_
                out[(size_t)(m + b + 1) * D_ + n] = lv;
            }
        }
    }
}

// ---------------------------------------------------------------------------
// K2: per-(b,t) row cumsum over features. ws: log_f -> a*; out: lv -> u=lv-a*
//   (8192 blocks, 4 rows each — max parallelism; R2-proven)
// ---------------------------------------------------------------------------
__global__ __launch_bounds__(256) void k_cumsum(
    float* __restrict__ ws_a, float* __restrict__ out)
{
    const int tid  = threadIdx.x;
    const int lane = tid & 63;
    const int row  = blockIdx.x * 4 + (tid >> 6);   // bt index
    const int b    = row >> 12;
    float* pa = ws_a + (size_t)row * D_;
    float* pu = out + (size_t)(row + b + 1) * D_;

    float vals[16];
#pragma unroll
    for (int j = 0; j < 4; ++j) {
        float4 v = *(const float4*)&pa[lane * 16 + j * 4];
        vals[j*4+0] = v.x; vals[j*4+1] = v.y; vals[j*4+2] = v.z; vals[j*4+3] = v.w;
    }
    float s = 0.0f;
#pragma unroll
    for (int j = 0; j < 16; ++j) s += vals[j];
    float inc = s;
#pragma unroll
    for (int off = 1; off < 64; off <<= 1) {
        float nv = __shfl_up(inc, off);
        if (lane >= off) inc += nv;
    }
    float run = inc - s;                       // exclusive prefix of lane sums
#pragma unroll
    for (int j = 0; j < 16; ++j) { run += vals[j]; vals[j] = run; }  // a*
#pragma unroll
    for (int j = 0; j < 4; ++j) {
        float4 lv4 = *(const float4*)&pu[lane * 16 + j * 4];
        float4 a4; a4.x = vals[j*4]; a4.y = vals[j*4+1]; a4.z = vals[j*4+2]; a4.w = vals[j*4+3];
        float4 u4; u4.x = lv4.x - a4.x; u4.y = lv4.y - a4.y;
                   u4.z = lv4.z - a4.z; u4.w = lv4.w - a4.w;
        *(float4*)&pa[lane * 16 + j * 4] = a4;
        *(float4*)&pu[lane * 16 + j * 4] = u4;
    }
}

// ---------------------------------------------------------------------------
// K3: per-chunk logsumexp totals of u over rows [1+64c, 64+64c].
//   Dual accumulators over t-parity break the dependent exp chain; unroll 4
//   batches loads for latency hiding.
// ---------------------------------------------------------------------------
__global__ __launch_bounds__(256) void k_chunk(
    const float* __restrict__ out, float* __restrict__ ctm, float* __restrict__ cts)
{
    int c = blockIdx.x, b = blockIdx.y;
    int d = threadIdx.x * 4;                   // 256 threads cover 1024 d
    const float* p = out + ((size_t)b * TP1 + 1 + c * CH) * D_ + d;
    float m0[4], s0[4], m1[4], s1[4];
#pragma unroll
    for (int e = 0; e < 4; ++e) {
        m0[e] = -__builtin_inff(); s0[e] = 0.0f;
        m1[e] = -__builtin_inff(); s1[e] = 0.0f;
    }
#pragma unroll 4
    for (int i = 0; i < CH; i += 2) {
        float4 ua = *(const float4*)(p + (size_t)i * D_);
        float4 ub = *(const float4*)(p + (size_t)(i + 1) * D_);
        lse_upd(m0[0], s0[0], ua.x); lse_upd(m0[1], s0[1], ua.y);
        lse_upd(m0[2], s0[2], ua.z); lse_upd(m0[3], s0[3], ua.w);
        lse_upd(m1[0], s1[0], ub.x); lse_upd(m1[1], s1[1], ub.y);
        lse_upd(m1[2], s1[2], ub.z); lse_upd(m1[3], s1[3], ub.w);
    }
    size_t ci = ((size_t)b * NCH + c) * D_ + d;
    float4 M4, S4;
    {
        float M, S;
#define MERGE(e, dst_m, dst_s)                                        \
        M = fmaxf(m0[e], m1[e]);                                      \
        S = s0[e] * __expf(m0[e] - M) + s1[e] * __expf(m1[e] - M);    \
        dst_m = M; dst_s = S;
        MERGE(0, M4.x, S4.x); MERGE(1, M4.y, S4.y);
        MERGE(2, M4.z, S4.z); MERGE(3, M4.w, S4.w);
#undef MERGE
    }
    *(float4*)&ctm[ci] = M4;
    *(float4*)&cts[ci] = S4;
}

// ---------------------------------------------------------------------------
// K4: exclusive chunk-carry logcumsumexp across chunks, seeded with row 0
//   (u0 = log_g(h0)); also writes out row 0 = exp(u0). s starts at 1 -> no
//   -inf handling anywhere downstream.
// ---------------------------------------------------------------------------
__global__ __launch_bounds__(256) void k_carry(
    const float* __restrict__ h0, const float* __restrict__ ctm,
    const float* __restrict__ cts, float* __restrict__ carry,
    float* __restrict__ out)
{
    int i = blockIdx.x * 256 + threadIdx.x;    // 0..8191
    int b = i >> 10, d = i & 1023;
    float u0 = log_g_f(h0[i]);
    out[(size_t)b * TP1 * D_ + d] = __expf(u0);   // h at t=0 (a*=0, lse=u0)
    float m = u0, s = 1.0f;
#pragma unroll 4
    for (int c = 0; c < NCH; ++c) {
        size_t ci = ((size_t)b * NCH + c) * D_ + d;
        carry[ci] = m + __logf(s);
        float m2 = ctm[ci], s2 = cts[ci];
        float M = fmaxf(m, m2);
        s = s * __expf(m - M) + s2 * __expf(m2 - M);
        m = M;
    }
}

// ---------------------------------------------------------------------------
// K5: finalize rows [1+64c, 64+64c]: rescan with carry-in (m=carry, s=1),
//   out = exp(a* + m) * s
// ---------------------------------------------------------------------------
__global__ __launch_bounds__(256) void k_final(
    const float* __restrict__ ws_a, const float* __restrict__ carry,
    float* __restrict__ out)
{
    int c = blockIdx.x, b = blockIdx.y;
    int d = threadIdx.x * 4;
    int t0 = 1 + c * CH;
    float4 v = *(const float4*)&carry[((size_t)b * NCH + c) * D_ + d];
    float4 m = v;
    float4 s = make_float4(1.f, 1.f, 1.f, 1.f);
#pragma unroll 2
    for (int i = 0; i < CH; ++i) {
        int t = t0 + i;
        size_t oi = ((size_t)b * TP1 + t) * D_ + d;
        float4 u = *(const float4*)&out[oi];
        float4 a = *(const float4*)&ws_a[((size_t)b * T_ + (t - 1)) * D_ + d];
        float4 mn;
        mn.x = fmaxf(m.x, u.x); mn.y = fmaxf(m.y, u.y);
        mn.z = fmaxf(m.z, u.z); mn.w = fmaxf(m.w, u.w);
        s.x = s.x * __expf(m.x - mn.x) + __expf(u.x - mn.x);
        s.y = s.y * __expf(m.y - mn.y) + __expf(u.y - mn.y);
        s.z = s.z * __expf(m.z - mn.z) + __expf(u.z - mn.z);
        s.w = s.w * __expf(m.w - mn.w) + __expf(u.w - mn.w);
        m = mn;
        float4 o;
        o.x = __expf(a.x + mn.x) * s.x;
        o.y = __expf(a.y + mn.y) * s.y;
        o.z = __expf(a.z + mn.z) * s.z;
        o.w = __expf(a.w + mn.w) * s.w;
        *(float4*)&out[oi] = o;
    }
}

// ---------------------------------------------------------------------------
extern "C" void kernel_launch(void* const* d_in, const int* in_sizes, int n_in,
                              void* d_out, int out_size, void* d_ws, size_t ws_size,
                              hipStream_t stream)
{
    const float* X   = (const float*)d_in[0];
    const float* h0  = (const float*)d_in[1];
    const float* Wi  = (const float*)d_in[2];
    const float* bi  = (const float*)d_in[3];
    const float* Wf  = (const float*)d_in[4];
    const float* bfv = (const float*)d_in[5];
    const float* Wh  = (const float*)d_in[6];
    const float* bh  = (const float*)d_in[7];
    float* out  = (float*)d_out;

    // ws layout:
    //   [0, 128M)        ws_a  (log_f -> a*)            fp32 M*D
    //   [128M, 192M)     Xs    f16 swizzled X           (dead after k_gemm)
    //   [192M, 198M)     Wsv   f16 swizzled Wi|Wf|Wh
    //   ctm/cts/carry overlay the Xs region after k_gemm (~6 MB)
    char* wsb = (char*)d_ws;
    float*    ws_a = (float*)wsb;
    _Float16* Xs   = (_Float16*)(wsb + (size_t)M_ * D_ * 4);
    _Float16* Wsv  = (_Float16*)(wsb + (size_t)M_ * D_ * 4 + (size_t)M_ * K_ * 2);
    float* ctm   = (float*)(wsb + (size_t)M_ * D_ * 4);
    float* cts   = ctm + B_ * NCH * D_;
    float* carry = cts + B_ * NCH * D_;

    k_cvt<<<1536 + M_ * K_ / 8 / 256, 256, 0, stream>>>(X, Wi, Wf, Wh, Xs, Wsv);

    dim3 g1(D_ / BLK_N, M_ / BLK_M);          // 16 x 256
    k_gemm<<<g1, 256, 0, stream>>>(Xs, Wsv, bi, bfv, bh, ws_a, out);
    k_cumsum<<<M_ / 4, 256, 0, stream>>>(ws_a, out);
    k_chunk<<<dim3(NCH, B_), 256, 0, stream>>>(out, ctm, cts);
    k_carry<<<32, 256, 0, stream>>>(h0, ctm, cts, carry, out);
    k_final<<<dim3(NCH, B_), 256, 0, stream>>>(ws_a, carry, out);
}